// Round 2
// baseline (217.802 us; speedup 1.0000x reference)
//
#include <hip/hip_runtime.h>
#include <hip/hip_bf16.h>
#include <math.h>
#include <float.h>

// Problem constants (x: [8192,128] f32, n_images=2)
static constexpr int NN    = 8192;
static constexpr int DD    = 128;
static constexpr int PP    = 4096;               // persons
static constexpr int TILE2 = 256;
static constexpr int TT2   = NN / TILE2;         // 32 tiles per dim
static constexpr int NBLK2 = TT2 * (TT2 + 1) / 2; // 528 upper-tri tile pairs
static constexpr int NC    = NBLK2 * 2;          // 2 candidates per tile block
static constexpr int GRP   = 2112;               // 8 rows x 256B + 64B pad
static constexpr int TLDS  = 32 * GRP;           // 67584 B per 256x128 bf16 tile
static constexpr int SMEM  = 2 * TLDS + 256;     // A + B + reduction scratch

struct Cand { float v; unsigned idx; };

using short8 = __attribute__((ext_vector_type(8))) short;
using f32x4  = __attribute__((ext_vector_type(4))) float;

typedef const __attribute__((address_space(1))) unsigned int* gas_uint;
typedef __attribute__((address_space(3))) unsigned int* las_uint;

// async 16B/lane global->LDS DMA. LDS dest = wave-uniform base + lane*16.
// Global address may vary per lane (gather). [m03/m97/m104]
__device__ __forceinline__ void dma16(const void* g, const void* l) {
    __builtin_amdgcn_global_load_lds(
        (gas_uint)(unsigned long long)g,
        (las_uint)(unsigned)(unsigned long long)l, 16, 0, 0);
}

__device__ __forceinline__ unsigned pk2(float lo, float hi) {
    unsigned a = (unsigned)__builtin_bit_cast(unsigned short, __float2bfloat16(lo));
    unsigned b = (unsigned)__builtin_bit_cast(unsigned short, __float2bfloat16(hi));
    return a | (b << 16);
}

__device__ __forceinline__ void push1(float& v1, unsigned& i1, float& v2, unsigned& i2,
                                      float w, unsigned j) {
    if (w > v1) { v2 = v1; i2 = i1; v1 = w; i1 = j; }
    else if (w > v2) { v2 = w; i2 = j; }
}

__device__ __forceinline__ void merge2(float& v1, unsigned& i1, float& v2, unsigned& i2,
                                       float w1, unsigned j1, float w2, unsigned j2) {
    if (w1 > v1) {
        float nv2; unsigned ni2;
        if (v1 >= w2) { nv2 = v1; ni2 = i1; } else { nv2 = w2; ni2 = j2; }
        v1 = w1; i1 = j1; v2 = nv2; i2 = ni2;
    } else if (w1 > v2) {
        v2 = w1; i2 = j1;
    }
}

// ---- kernel 0: x -> bf16 copy (once) + sim_self in double ----
__global__ __launch_bounds__(256) void k_prep(const float* __restrict__ x,
                                              unsigned short* __restrict__ xb,
                                              double* __restrict__ ss) {
    const int tid = threadIdx.x;
    if (blockIdx.x < 256) {
        // 65536 chunks x 16 floats -> 16 bf16
        int chunk = blockIdx.x * 256 + tid;
        const float4* s = (const float4*)(x + (size_t)chunk * 16);
        float4 f0 = s[0], f1 = s[1], f2 = s[2], f3 = s[3];
        uint4 o0 = {pk2(f0.x, f0.y), pk2(f0.z, f0.w), pk2(f1.x, f1.y), pk2(f1.z, f1.w)};
        uint4 o1 = {pk2(f2.x, f2.y), pk2(f2.z, f2.w), pk2(f3.x, f3.y), pk2(f3.z, f3.w)};
        uint4* d = (uint4*)(xb + (size_t)chunk * 16);
        d[0] = o0; d[1] = o1;
    } else {
        // 64 blocks: sim_self[p] = dot(x[p], x[p+1]) in double, wave per person
        int b = blockIdx.x - 256;          // 0..63
        const int wv = tid >> 6, lane = tid & 63;
        #pragma unroll 4
        for (int u = 0; u < 16; ++u) {
            int p = b * 64 + wv * 16 + u;  // 0..4095
            const float* a  = x + (size_t)p * DD;
            const float* bb = a + DD;
            double s = (double)a[lane] * (double)bb[lane]
                     + (double)a[lane + 64] * (double)bb[lane + 64];
            #pragma unroll
            for (int off = 32; off >= 1; off >>= 1) s += __shfl_down(s, off);
            if (lane == 0) ss[p] = s;
        }
    }
}

// ---- kernel 1: MFMA top-2 over upper triangle of G = xb xb^T.
// 256x256 tile per block (8 waves, each 128x64 output), single K-phase:
// stage full K=128 for both 256-row panels via global_load_lds (132KB dynamic
// LDS), ONE barrier, then 4 K-chunks of MFMA from swizzled LDS.
// 528 blocks (4x fewer prologue/epilogue/convoy than 128^2 tiling),
// staged L2 traffic halved by 8-wave panel sharing. ----
__global__ __launch_bounds__(512, 2) void k_top2(const unsigned short* __restrict__ xb,
                                                 Cand* __restrict__ cands) {
    extern __shared__ __align__(16) char smem[];
    char* As = smem;
    char* Bs = smem + TLDS;
    float*    sv1 = (float*)(smem + 2 * TLDS);
    float*    sv2 = sv1 + 8;
    unsigned* si1 = (unsigned*)(sv2 + 8);
    unsigned* si2 = si1 + 8;

    const int tid  = threadIdx.x;
    const int wv   = tid >> 6;      // wave 0..7
    const int lane = tid & 63;

    // decode linear block id -> (Ti, Tj), Ti <= Tj (256-row tiles)
    int rem = blockIdx.x;
    int Ti = 0;
    while (rem >= TT2 - Ti) { rem -= (TT2 - Ti); ++Ti; }
    const int Tj = Ti + rem;

    // ---- stage: waves 0-3 DMA the A panel, waves 4-7 the B panel.
    // LDS group = 8 rows x 256B (+64B pad). Source column is XOR-swizzled
    // (col ^= (row&7)<<4) so the linear LDS write yields conflict-reduced reads.
    {
        const unsigned short* srcbase =
            xb + (size_t)((wv < 4 ? Ti : Tj) * TILE2) * DD;
        char* ldsT = (wv < 4) ? As : Bs;
        const int gbase = (wv & 3) * 8;
        const int grow4 = lane >> 4;        // row within 4-row DMA slab 0..3
        const int chunk = lane & 15;        // 16B chunk within 256B row
        #pragma unroll
        for (int t = 0; t < 8; ++t) {
            int g = gbase + t;              // group 0..31 within panel
            #pragma unroll
            for (int h = 0; h < 2; ++h) {
                int rin  = h * 4 + grow4;   // row within group 0..7
                int row  = g * 8 + rin;     // row within 256-row panel
                int colb = (chunk * 16) ^ (rin << 4);
                dma16((const char*)srcbase + (size_t)row * 256 + colb,
                      ldsT + g * GRP + h * 1024);
            }
        }
    }
    __syncthreads();   // compiler emits vmcnt(0) before s_barrier -> DMA landed

    const int wm   = wv >> 2;       // wave row-half 0..1 (128 rows)
    const int wn   = wv & 3;        // wave col-quarter 0..3 (64 cols)
    const int quad = lane >> 4;     // 0..3
    const int r16  = lane & 15;     // 0..15
    const int rlow = r16 & 7;
    const int xa   = rlow << 4;     // XOR term matching the staging swizzle

    // per-lane fragment base addresses (group*GRP + (row&7)*256)
    const char* Abase = As + (wm * 16 + (r16 >> 3)) * GRP + rlow * 256;
    const char* Bbase = Bs + (wn * 8  + (r16 >> 3)) * GRP + rlow * 256;

    f32x4 acc[8][4];
    #pragma unroll
    for (int mi = 0; mi < 8; ++mi)
        #pragma unroll
        for (int nj = 0; nj < 4; ++nj)
            acc[mi][nj] = (f32x4){0.f, 0.f, 0.f, 0.f};

    #pragma unroll
    for (int kc = 0; kc < 4; ++kc) {        // 4 chunks of K=32
        const int co = (quad * 16 + kc * 64) ^ xa;
        short8 af[8];
        #pragma unroll
        for (int mi = 0; mi < 8; ++mi)
            af[mi] = *(const short8*)(Abase + mi * (2 * GRP) + co);
        #pragma unroll
        for (int nj = 0; nj < 4; ++nj) {
            short8 bf = *(const short8*)(Bbase + nj * (2 * GRP) + co);
            #pragma unroll
            for (int mi = 0; mi < 8; ++mi)
                acc[mi][nj] = __builtin_amdgcn_mfma_f32_16x16x32_bf16(
                    af[mi], bf, acc[mi][nj], 0, 0, 0);
        }
    }

    // ---- epilogue: per-lane top-2 over valid (i<j) ----
    // C/D layout: col = lane&15, row = (lane>>4)*4 + reg  [verified earlier]
    const int ibase = Ti * TILE2 + wm * 128;
    const int jbase = Tj * TILE2 + wn * 64;
    float v1 = -INFINITY, v2 = -INFINITY;
    unsigned i1 = 0, i2 = 0;
    #pragma unroll
    for (int mi = 0; mi < 8; ++mi) {
        #pragma unroll
        for (int nj = 0; nj < 4; ++nj) {
            int gj = jbase + nj * 16 + r16;
            #pragma unroll
            for (int reg = 0; reg < 4; ++reg) {
                int gi = ibase + mi * 16 + quad * 4 + reg;
                if (gi < gj) {
                    unsigned idx = (unsigned)(gi * NN + gj);
                    push1(v1, i1, v2, i2, acc[mi][nj][reg], idx);
                }
            }
        }
    }

    #pragma unroll
    for (int off = 32; off >= 1; off >>= 1) {
        float    w1 = __shfl_down(v1, off);
        unsigned j1 = (unsigned)__shfl_down((int)i1, off);
        float    w2 = __shfl_down(v2, off);
        unsigned j2 = (unsigned)__shfl_down((int)i2, off);
        merge2(v1, i1, v2, i2, w1, j1, w2, j2);
    }
    if (lane == 0) { sv1[wv] = v1; si1[wv] = i1; sv2[wv] = v2; si2[wv] = i2; }
    __syncthreads();
    if (tid == 0) {
        for (int w = 1; w < 8; ++w)
            merge2(v1, i1, v2, i2, sv1[w], si1[w], sv2[w], si2[w]);
        cands[blockIdx.x * 2]     = {v1, i1};
        cands[blockIdx.x * 2 + 1] = {v2, i2};
    }
}

// ---- kernel 2: approx top-2 -> exact recheck (double) -> final mean ----
__global__ __launch_bounds__(1024) void k_final(const float* __restrict__ x,
                                                const double* __restrict__ ss,
                                                const Cand* __restrict__ cands,
                                                float* __restrict__ out) {
    __shared__ float redv[32];          // 16 waves x 2
    __shared__ float s_thresh;
    __shared__ int cnt;
    __shared__ unsigned qidx[128];
    __shared__ double qex[128];
    __shared__ double sd1, sd2;
    __shared__ unsigned stopi;
    __shared__ double sacc[1024];

    const int tid  = threadIdx.x;
    const int wv   = tid >> 6;          // 0..15
    const int lane = tid & 63;
    if (tid == 0) cnt = 0;

    // Phase A: approx global top-2 VALUES
    float v1 = -INFINITY, v2 = -INFINITY;
    for (int e = tid; e < NC; e += 1024) {
        float v = cands[e].v;
        if (v > v1) { v2 = v1; v1 = v; }
        else if (v > v2) v2 = v;
    }
    #pragma unroll
    for (int off = 32; off >= 1; off >>= 1) {
        float w1 = __shfl_down(v1, off);
        float w2 = __shfl_down(v2, off);
        if (w1 > v1) { v2 = (v1 >= w2) ? v1 : w2; v1 = w1; }
        else if (w1 > v2) v2 = w1;
    }
    if (lane == 0) { redv[wv * 2] = v1; redv[wv * 2 + 1] = v2; }
    __syncthreads();
    if (tid == 0) {
        float a1 = -INFINITY, a2 = -INFINITY;
        for (int e = 0; e < 32; ++e) {
            float v = redv[e];
            if (v > a1) { a2 = a1; a1 = v; }
            else if (v > a2) a2 = v;
        }
        s_thresh = a2 - 1.0f;   // margin >> bf16 dot-product error bound (~0.3)
    }
    __syncthreads();
    const float thresh = s_thresh;

    // Phase B: gather all candidates within margin of approx top-2
    for (int e = tid; e < NC; e += 1024) {
        if (cands[e].v >= thresh) {
            int k = atomicAdd(&cnt, 1);
            if (k < 128) qidx[k] = cands[e].idx;
        }
    }
    __syncthreads();
    const int n = cnt < 128 ? cnt : 128;

    // Phase C: exact double dot for each qualifying candidate (one wave each)
    for (int c = wv; c < n; c += 16) {
        unsigned idx = qidx[c];
        unsigned gi = idx >> 13;       // / 8192
        unsigned gj = idx & 8191;
        const float* pa = x + (size_t)gi * DD;
        const float* pb = x + (size_t)gj * DD;
        double s = (double)pa[lane] * (double)pb[lane]
                 + (double)pa[lane + 64] * (double)pb[lane + 64];
        #pragma unroll
        for (int off = 32; off >= 1; off >>= 1) s += __shfl_down(s, off);
        if (lane == 0) qex[c] = s;
    }
    __syncthreads();

    // Phase D: exact top-2 over rechecked candidates
    if (tid == 0) {
        double d1 = -DBL_MAX, d2 = -DBL_MAX;
        unsigned bi = 0;
        for (int c = 0; c < n; ++c) {
            double v = qex[c];
            if (v > d1) { d2 = d1; d1 = v; bi = qidx[c]; }
            else if (v > d2) d2 = v;
        }
        sd1 = d1; sd2 = d2; stopi = bi;
    }
    __syncthreads();

    const double top1 = sd1, top2 = sd2;
    const unsigned topi = stopi;

    // Phase E: mean(sim_oth / sim_self)
    double acc = 0.0;
    for (int p = tid; p < PP; p += 1024) {
        unsigned selfidx = (unsigned)(p * NN + p + 1);
        double so = (topi == selfidx) ? top2 : top1;
        acc += so / ss[p];
    }
    sacc[tid] = acc;
    __syncthreads();
    for (int s = 512; s >= 1; s >>= 1) {
        if (tid < s) sacc[tid] += sacc[tid + s];
        __syncthreads();
    }
    if (tid == 0) out[0] = (float)(sacc[0] / (double)PP);
}

extern "C" void kernel_launch(void* const* d_in, const int* in_sizes, int n_in,
                              void* d_out, int out_size, void* d_ws, size_t ws_size,
                              hipStream_t stream) {
    (void)in_sizes; (void)n_in; (void)out_size; (void)ws_size;
    const float* x = (const float*)d_in[0];
    float* out = (float*)d_out;

    double* ss  = (double*)d_ws;                                  // 32 KB
    Cand* cands = (Cand*)((char*)d_ws + PP * sizeof(double));     // ~8.5 KB
    unsigned short* xb = (unsigned short*)((char*)d_ws + 131072); // 2 MB bf16 copy

    hipFuncSetAttribute((const void*)k_top2,
                        hipFuncAttributeMaxDynamicSharedMemorySize, SMEM);

    k_prep<<<320, 256, 0, stream>>>(x, xb, ss);
    k_top2<<<NBLK2, 512, SMEM, stream>>>(xb, cands);
    k_final<<<1, 1024, 0, stream>>>(x, ss, cands, out);
}

// Round 3
// 183.975 us; speedup vs baseline: 1.1839x; 1.1839x over previous
//
#include <hip/hip_runtime.h>
#include <hip/hip_bf16.h>
#include <math.h>
#include <float.h>

// Problem constants (x: [8192,128] f32, n_images=2)
static constexpr int NN    = 8192;
static constexpr int DD    = 128;
static constexpr int PP    = 4096;              // persons
static constexpr int TILE  = 128;
static constexpr int TT    = NN / TILE;         // 64 tiles per dim
static constexpr int NBLK  = TT * (TT + 1) / 2; // 2080 upper-tri tile pairs
static constexpr int NC    = NBLK * 2;          // 2 candidates per tile block
static constexpr int GRP   = 1088;              // 8 rows x 128B (fp8) + 64B pad
static constexpr int PLDS  = 16 * GRP;          // 17408 B per 128x128 fp8 panel

struct Cand { float v; unsigned idx; };

using f32x4 = __attribute__((ext_vector_type(4))) float;

typedef const __attribute__((address_space(1))) unsigned int* gas_uint;
typedef __attribute__((address_space(3))) unsigned int* las_uint;

// async 16B/lane global->LDS DMA. LDS dest = wave-uniform base + lane*16.
// Global address may vary per lane. [m03/m97/m104]
__device__ __forceinline__ void dma16(const void* g, const void* l) {
    __builtin_amdgcn_global_load_lds(
        (gas_uint)(unsigned long long)g,
        (las_uint)(unsigned)(unsigned long long)l, 16, 0, 0);
}

__device__ __forceinline__ void push1(float& v1, unsigned& i1, float& v2, unsigned& i2,
                                      float w, unsigned j) {
    if (w > v1) { v2 = v1; i2 = i1; v1 = w; i1 = j; }
    else if (w > v2) { v2 = w; i2 = j; }
}

__device__ __forceinline__ void merge2(float& v1, unsigned& i1, float& v2, unsigned& i2,
                                       float w1, unsigned j1, float w2, unsigned j2) {
    if (w1 > v1) {
        float nv2; unsigned ni2;
        if (v1 >= w2) { nv2 = v1; ni2 = i1; } else { nv2 = w2; ni2 = j2; }
        v1 = w1; i1 = j1; v2 = nv2; i2 = ni2;
    } else if (w1 > v2) {
        v2 = w1; i2 = j1;
    }
}

// ---- kernel 0: x -> fp8 e4m3 copy (1MB) + sim_self in double ----
__global__ __launch_bounds__(256) void k_prep(const float* __restrict__ x,
                                              unsigned char* __restrict__ xb,
                                              double* __restrict__ ss) {
    const int tid = threadIdx.x;
    if (blockIdx.x < 256) {
        // 65536 chunks x 16 floats -> 16 fp8 (16B out per thread)
        int chunk = blockIdx.x * 256 + tid;
        const float4* s = (const float4*)(x + (size_t)chunk * 16);
        float4 f0 = s[0], f1 = s[1], f2 = s[2], f3 = s[3];
        unsigned w0 = 0, w1 = 0, w2 = 0, w3 = 0;
        w0 = __builtin_amdgcn_cvt_pk_fp8_f32(f0.x, f0.y, w0, false);
        w0 = __builtin_amdgcn_cvt_pk_fp8_f32(f0.z, f0.w, w0, true);
        w1 = __builtin_amdgcn_cvt_pk_fp8_f32(f1.x, f1.y, w1, false);
        w1 = __builtin_amdgcn_cvt_pk_fp8_f32(f1.z, f1.w, w1, true);
        w2 = __builtin_amdgcn_cvt_pk_fp8_f32(f2.x, f2.y, w2, false);
        w2 = __builtin_amdgcn_cvt_pk_fp8_f32(f2.z, f2.w, w2, true);
        w3 = __builtin_amdgcn_cvt_pk_fp8_f32(f3.x, f3.y, w3, false);
        w3 = __builtin_amdgcn_cvt_pk_fp8_f32(f3.z, f3.w, w3, true);
        uint4 o = {w0, w1, w2, w3};
        *(uint4*)(xb + (size_t)chunk * 16) = o;
    } else {
        // 64 blocks: sim_self[p] = dot(x[p], x[p+1]) in double, wave per person
        int b = blockIdx.x - 256;          // 0..63
        const int wv = tid >> 6, lane = tid & 63;
        #pragma unroll 4
        for (int u = 0; u < 16; ++u) {
            int p = b * 64 + wv * 16 + u;  // 0..4095
            const float* a  = x + (size_t)p * DD;
            const float* bb = a + DD;
            double s = (double)a[lane] * (double)bb[lane]
                     + (double)a[lane + 64] * (double)bb[lane + 64];
            #pragma unroll
            for (int off = 32; off >= 1; off >>= 1) s += __shfl_down(s, off);
            if (lane == 0) ss[p] = s;
        }
    }
}

// ---- kernel 1: fp8 MFMA top-2 over upper triangle of G = xb xb^T.
// 128x128 tiles, full K=128 staged in ONE phase (fp8 halves bytes): 35KB LDS
// -> 4 resident blocks/CU (max concurrent miss bursts), one barrier per block.
// XOR-swizzled DMA source kills ds_read bank conflicts. ----
__global__ __launch_bounds__(256, 4) void k_top2(const unsigned char* __restrict__ xb,
                                                 Cand* __restrict__ cands) {
    __shared__ __align__(16) char As[PLDS];
    __shared__ __align__(16) char Bs[PLDS];
    __shared__ float sv1[4], sv2[4];
    __shared__ unsigned si1[4], si2[4];

    const int tid  = threadIdx.x;
    const int wv   = tid >> 6;      // wave 0..3
    const int lane = tid & 63;

    // decode linear block id -> (ti, tj), ti <= tj
    int rem = blockIdx.x;
    int ti = 0;
    while (rem >= TT - ti) { rem -= (TT - ti); ++ti; }
    const int tj = ti + rem;

    // ---- stage both 128x128 fp8 panels, single phase, 8 dma16 per wave.
    // group = 8 rows x 128B. lane l: row_in = l>>3, 16B-chunk = l&7.
    // Source col XOR-swizzled by (row_in<<4) so linear LDS write gives
    // conflict-free fragment reads.
    {
        const int grow = lane >> 3;                 // 0..7
        const int colb = ((lane & 7) * 16) ^ (grow << 4);
        #pragma unroll
        for (int t = 0; t < 4; ++t) {
            int g = wv * 4 + t;                     // group 0..15
            dma16(xb + (size_t)(ti * TILE + g * 8 + grow) * DD + colb, As + g * GRP);
            dma16(xb + (size_t)(tj * TILE + g * 8 + grow) * DD + colb, Bs + g * GRP);
        }
    }
    __syncthreads();   // compiler emits vmcnt(0) before s_barrier -> DMA landed

    const int wm   = wv >> 1;       // wave row 0..1 (64 rows)
    const int wn   = wv & 1;        // wave col 0..1 (64 cols)
    const int quad = lane >> 4;     // 0..3
    const int r16  = lane & 15;     // 0..15
    const int rl   = r16 & 7;       // row within group
    const int rh   = r16 >> 3;      // group parity within 16-row fragment
    const int xs   = rl << 4;       // XOR term matching the staging swizzle

    // fragment byte: global col = kc*32 + quad*8 (8 fp8 = one i64 operand)
    const char* Abase = As + (wm * 8 + rh) * GRP + rl * 128 + (quad & 1) * 8;
    const char* Bbase = Bs + (wn * 8 + rh) * GRP + rl * 128 + (quad & 1) * 8;

    f32x4 acc[4][4];
    #pragma unroll
    for (int mi = 0; mi < 4; ++mi)
        #pragma unroll
        for (int nj = 0; nj < 4; ++nj)
            acc[mi][nj] = (f32x4){0.f, 0.f, 0.f, 0.f};

    #pragma unroll
    for (int kc = 0; kc < 4; ++kc) {        // 4 chunks of K=32
        const int co = (kc * 32 + (quad >> 1) * 16) ^ xs;
        long af[4], bq[4];
        #pragma unroll
        for (int mi = 0; mi < 4; ++mi) {
            af[mi] = *(const long*)(Abase + mi * (2 * GRP) + co);
            bq[mi] = *(const long*)(Bbase + mi * (2 * GRP) + co);
        }
        #pragma unroll
        for (int mi = 0; mi < 4; ++mi)
            #pragma unroll
            for (int nj = 0; nj < 4; ++nj)
                acc[mi][nj] = __builtin_amdgcn_mfma_f32_16x16x32_fp8_fp8(
                    af[mi], bq[nj], acc[mi][nj], 0, 0, 0);
    }

    // ---- epilogue: per-lane top-2 over valid (i<j) ----
    // C/D layout: col = lane&15, row = (lane>>4)*4 + reg (dtype-independent)
    const int ibase = ti * TILE + wm * 64;
    const int jbase = tj * TILE + wn * 64;
    float v1 = -INFINITY, v2 = -INFINITY;
    unsigned i1 = 0, i2 = 0;
    #pragma unroll
    for (int mi = 0; mi < 4; ++mi) {
        #pragma unroll
        for (int nj = 0; nj < 4; ++nj) {
            int gj = jbase + nj * 16 + r16;
            #pragma unroll
            for (int reg = 0; reg < 4; ++reg) {
                int gi = ibase + mi * 16 + quad * 4 + reg;
                if (gi < gj) {
                    unsigned idx = (unsigned)(gi * NN + gj);
                    push1(v1, i1, v2, i2, acc[mi][nj][reg], idx);
                }
            }
        }
    }

    #pragma unroll
    for (int off = 32; off >= 1; off >>= 1) {
        float    w1 = __shfl_down(v1, off);
        unsigned j1 = (unsigned)__shfl_down((int)i1, off);
        float    w2 = __shfl_down(v2, off);
        unsigned j2 = (unsigned)__shfl_down((int)i2, off);
        merge2(v1, i1, v2, i2, w1, j1, w2, j2);
    }
    if (lane == 0) { sv1[wv] = v1; si1[wv] = i1; sv2[wv] = v2; si2[wv] = i2; }
    __syncthreads();
    if (tid == 0) {
        for (int w = 1; w < 4; ++w)
            merge2(v1, i1, v2, i2, sv1[w], si1[w], sv2[w], si2[w]);
        cands[blockIdx.x * 2]     = {v1, i1};
        cands[blockIdx.x * 2 + 1] = {v2, i2};
    }
}

// ---- kernel 2: approx top-2 -> exact recheck (double) -> final mean ----
// Margin widened to 10.0 for fp8 approximation error (RMS ~0.7, 10 = 14 sigma);
// recheck capacity 256 (expected ~60 candidates). Final value is computed from
// exact f64 dots, so output is independent of the fp8 approximation.
__global__ __launch_bounds__(1024) void k_final(const float* __restrict__ x,
                                                const double* __restrict__ ss,
                                                const Cand* __restrict__ cands,
                                                float* __restrict__ out) {
    __shared__ float redv[32];          // 16 waves x 2
    __shared__ float s_thresh;
    __shared__ int cnt;
    __shared__ unsigned qidx[256];
    __shared__ double qex[256];
    __shared__ double sd1, sd2;
    __shared__ unsigned stopi;
    __shared__ double sacc[1024];

    const int tid  = threadIdx.x;
    const int wv   = tid >> 6;          // 0..15
    const int lane = tid & 63;
    if (tid == 0) cnt = 0;

    // Phase A: approx global top-2 VALUES
    float v1 = -INFINITY, v2 = -INFINITY;
    for (int e = tid; e < NC; e += 1024) {
        float v = cands[e].v;
        if (v > v1) { v2 = v1; v1 = v; }
        else if (v > v2) v2 = v;
    }
    #pragma unroll
    for (int off = 32; off >= 1; off >>= 1) {
        float w1 = __shfl_down(v1, off);
        float w2 = __shfl_down(v2, off);
        if (w1 > v1) { v2 = (v1 >= w2) ? v1 : w2; v1 = w1; }
        else if (w1 > v2) v2 = w1;
    }
    if (lane == 0) { redv[wv * 2] = v1; redv[wv * 2 + 1] = v2; }
    __syncthreads();
    if (tid == 0) {
        float a1 = -INFINITY, a2 = -INFINITY;
        for (int e = 0; e < 32; ++e) {
            float v = redv[e];
            if (v > a1) { a2 = a1; a1 = v; }
            else if (v > a2) a2 = v;
        }
        s_thresh = a2 - 10.0f;   // margin >> fp8 dot-product error bound
    }
    __syncthreads();
    const float thresh = s_thresh;

    // Phase B: gather all candidates within margin of approx top-2
    for (int e = tid; e < NC; e += 1024) {
        if (cands[e].v >= thresh) {
            int k = atomicAdd(&cnt, 1);
            if (k < 256) qidx[k] = cands[e].idx;
        }
    }
    __syncthreads();
    const int n = cnt < 256 ? cnt : 256;

    // Phase C: exact double dot for each qualifying candidate (one wave each)
    for (int c = wv; c < n; c += 16) {
        unsigned idx = qidx[c];
        unsigned gi = idx >> 13;       // / 8192
        unsigned gj = idx & 8191;
        const float* pa = x + (size_t)gi * DD;
        const float* pb = x + (size_t)gj * DD;
        double s = (double)pa[lane] * (double)pb[lane]
                 + (double)pa[lane + 64] * (double)pb[lane + 64];
        #pragma unroll
        for (int off = 32; off >= 1; off >>= 1) s += __shfl_down(s, off);
        if (lane == 0) qex[c] = s;
    }
    __syncthreads();

    // Phase D: exact top-2 over rechecked candidates
    if (tid == 0) {
        double d1 = -DBL_MAX, d2 = -DBL_MAX;
        unsigned bi = 0;
        for (int c = 0; c < n; ++c) {
            double v = qex[c];
            if (v > d1) { d2 = d1; d1 = v; bi = qidx[c]; }
            else if (v > d2) d2 = v;
        }
        sd1 = d1; sd2 = d2; stopi = bi;
    }
    __syncthreads();

    const double top1 = sd1, top2 = sd2;
    const unsigned topi = stopi;

    // Phase E: mean(sim_oth / sim_self)
    double acc = 0.0;
    for (int p = tid; p < PP; p += 1024) {
        unsigned selfidx = (unsigned)(p * NN + p + 1);
        double so = (topi == selfidx) ? top2 : top1;
        acc += so / ss[p];
    }
    sacc[tid] = acc;
    __syncthreads();
    for (int s = 512; s >= 1; s >>= 1) {
        if (tid < s) sacc[tid] += sacc[tid + s];
        __syncthreads();
    }
    if (tid == 0) out[0] = (float)(sacc[0] / (double)PP);
}

extern "C" void kernel_launch(void* const* d_in, const int* in_sizes, int n_in,
                              void* d_out, int out_size, void* d_ws, size_t ws_size,
                              hipStream_t stream) {
    (void)in_sizes; (void)n_in; (void)out_size; (void)ws_size;
    const float* x = (const float*)d_in[0];
    float* out = (float*)d_out;

    double* ss  = (double*)d_ws;                                  // 32 KB
    Cand* cands = (Cand*)((char*)d_ws + PP * sizeof(double));     // ~33 KB
    unsigned char* xb = (unsigned char*)((char*)d_ws + 131072);   // 1 MB fp8 copy

    k_prep<<<320, 256, 0, stream>>>(x, xb, ss);
    k_top2<<<NBLK, 256, 0, stream>>>(xb, cands);
    k_final<<<1, 1024, 0, stream>>>(x, ss, cands, out);
}